// Round 2
// baseline (423.383 us; speedup 1.0000x reference)
//
#include <hip/hip_runtime.h>
#include <hip/hip_bf16.h>
#include <stdint.h>

// SelfAttention: B=8, N=2048, D=DQ=DV=1024, fp32 in/out, fp16 MFMA internally.
// Round 8 -> 9: rebalance the 4-phase schedule. R8 front-loaded all 16 A-frag
// ds_reads into phase 0 (18-read burst behind one lgkmcnt(0)), leaving phases
// 1-3 with an idle LDS pipe -> MfmaUtil stuck at 30%. New read distribution
// pairs each 16-MFMA cluster with ~the reads it can hide (m201 balance):
//   ph0: read a0(8)+bA(2) -> MFMA a0xbA   ; stage B1(t+1)->nxt
//   ph1: read a1(8)+bB(2) -> MFMA a0xbB   ; (lgkm(0) drains a1 too ->
//        ALL waves have drained cur.A by barrier-exit of ph1)
//   ph2: read bC(2)+bD(2) -> MFMA a1xbC   ; stage A0,A1(t+2)->cur  [A free]
//   ph3: no reads         -> MFMA a1xbD   ; stage B0(t+2)->cur     [B free
//        at B2(ph2): ph2's lgkm(0) drained bA..bD for every wave]
//        end-of-tile s_waitcnt vmcnt(6) (3 units in flight) -> tile t+1
//        fully resident; vmcnt(0) only for the last two tiles.
// Race-freedom: a region is (re)staged only after a barrier that every wave
// reaches strictly after its lgkmcnt(0) drain of all reads from that region.
// Unit flight schedule (16KB units, 2 global_load_lds each) unchanged from R8:
// prologue 7 units + per-tile {B1(t+1), A0(t+2), A1(t+2), B0(t+2)}.
//
// Workspace (224 MiB): unchanged layout.

typedef _Float16 f16;
typedef _Float16 f16x8 __attribute__((ext_vector_type(8)));
typedef _Float16 f16x4 __attribute__((ext_vector_type(4)));
typedef float f32x4 __attribute__((ext_vector_type(4)));

typedef __attribute__((address_space(3))) void lds_void;
typedef const __attribute__((address_space(1))) void gbl_void;

__device__ __forceinline__ void async16(void* l, const void* g) {
    __builtin_amdgcn_global_load_lds(
        reinterpret_cast<gbl_void*>(reinterpret_cast<uintptr_t>(g)),
        reinterpret_cast<lds_void*>(reinterpret_cast<uintptr_t>(l)),
        16, 0, 0);
}

// ---------------------------------------------------------------- cast x
__global__ __launch_bounds__(256) void cast_f32_f16(const float* __restrict__ x,
                                                    f16* __restrict__ y) {
    long i = (long)blockIdx.x * 256 + threadIdx.x;
    float4 v = reinterpret_cast<const float4*>(x)[i];
    f16x4 o = {(f16)v.x, (f16)v.y, (f16)v.z, (f16)v.w};
    reinterpret_cast<f16x4*>(y)[i] = o;
}

// ------------------------------------- transpose + cast Wq|Wk|Wv -> wt[3072][1024]
__global__ __launch_bounds__(256) void transpose_cast3(const float* __restrict__ W0,
                                                       const float* __restrict__ W1,
                                                       const float* __restrict__ W2,
                                                       f16* __restrict__ wt) {
    const float* W = blockIdx.z == 0 ? W0 : blockIdx.z == 1 ? W1 : W2;
    f16* o = wt + (long)blockIdx.z * 1024 * 1024;
    __shared__ float tile[32][33];
    int c0 = blockIdx.x * 32, r0 = blockIdx.y * 32;
    int tx = threadIdx.x, ty = threadIdx.y;
#pragma unroll
    for (int i = ty; i < 32; i += 8) tile[i][tx] = W[(long)(r0 + i) * 1024 + c0 + tx];
    __syncthreads();
#pragma unroll
    for (int i = ty; i < 32; i += 8) o[(long)(c0 + i) * 1024 + r0 + tx] = (f16)tile[tx][i];
}

// ---------------------------------------------------- 256x256 deep-pipe GEMM
// MODE 0: qkv  A=xh[16384x1024]   B=wt[3072x1024]   K=1024, grid 768
// MODE 1: qk^T A=Q  [b:2048x1024] B=Kb[b:2048x1024] K=1024, grid 512, f16 out
// MODE 2: pv   A=P  [b:2048x2048] B=Vt[b:1024x2048] K=2048, grid 256, f32 out
template <int MODE>
__global__ __launch_bounds__(512, 2) void gemm256(
    const f16* __restrict__ A, const f16* __restrict__ Bm,
    f16* __restrict__ o16, float* __restrict__ o32,
    const float* __restrict__ bq, const float* __restrict__ bk,
    const float* __restrict__ bv,
    f16* __restrict__ Qo, f16* __restrict__ Ko, f16* __restrict__ Vto) {
    constexpr int LDA = MODE == 2 ? 2048 : 1024;
    constexpr int LDB = MODE == 2 ? 2048 : 1024;
    constexpr int NT = (MODE == 2 ? 2048 : 1024) / 64;

    __shared__ f16 sm[65536];          // 128 KiB: [buf][A 32K | B 32K]
    char* smb = (char*)sm;

    const int tid = threadIdx.x;
    const int lane = tid & 63;
    const int wv = tid >> 6;           // 8 waves: 2M x 4N
    const int wmi = wv >> 2;           // 0..1  -> rows wmi*128
    const int wni = wv & 3;            // 0..3  -> cols wni*64

    const int L = blockIdx.x;
    long mBase, nBase, oOff = 0;
    int nx = 0;
    if (MODE == 0) {
        const int xcd = L & 7, j = L >> 3;   // j in [0,96): my fast, nx slow
        nx = j >> 3;
        mBase = (long)(xcd * 8 + (j & 7)) * 256;
        nBase = (long)nx * 256;
    } else if (MODE == 1) {
        const int b = L & 7, j = L >> 3;     // j in [0,64)
        mBase = (long)(j & 7) * 256;
        nBase = (long)(j >> 3) * 256;
        A += (long)b * 2048 * 1024;
        Bm += (long)b * 2048 * 1024;
        oOff = (long)b * 2048 * 2048;
    } else {
        const int b = L & 7, j = L >> 3;     // j in [0,32)
        mBase = (long)(j & 7) * 256;
        nBase = (long)(j >> 3) * 256;
        A += (long)b * 2048 * 2048;
        Bm += (long)b * 1024 * 2048;
        oOff = (long)b * 2048 * 1024;
    }

    // staging: unit = 128 rows x 64 cols f16 = 16KB; 2 async16/thread/unit.
    // LDS dest linear (wave-uniform + lane*16); source col pre-swizzled so
    // phys chunk c of row r holds global chunk c^(r&7).
    const int sru = tid >> 3;                    // 0..63
    const int sck = (tid & 7) ^ (sru & 7);       // swizzled source chunk
    const f16* pA = A + (mBase + sru) * LDA + sck * 8;
    const f16* pB = Bm + (nBase + sru) * LDB + sck * 8;

    auto stA = [&](int bufB, int half, int t) {
        const f16* s = pA + half * 128 * LDA + t * 64;
        char* d = smb + bufB + half * 16384 + tid * 16;
        async16(d, s);
        async16(d + 8192, s + 64 * LDA);
    };
    auto stB = [&](int bufB, int half, int t) {
        const f16* s = pB + half * 128 * LDB + t * 64;
        char* d = smb + bufB + 32768 + half * 16384 + tid * 16;
        async16(d, s);
        async16(d + 8192, s + 64 * LDB);
    };

    // fragment read bases (f16 element units); ks toggle = ^32 (chunk ^4)
    const int pc0 = (lane >> 4) ^ (lane & 7);
    const int aBase = (wmi * 128 + (lane & 15)) * 64 + pc0 * 8;
    const int bBase = 16384 + (wni * 64 + (lane & 15)) * 64 + pc0 * 8;

    // prologue: tile0 {A0,A1,B0,B1} -> buf0, tile1 {A0,A1,B0} -> buf1
    stA(0, 0, 0); stA(0, 1, 0); stB(0, 0, 0); stB(0, 1, 0);
    stA(65536, 0, 1); stA(65536, 1, 1); stB(65536, 0, 1);
    asm volatile("s_waitcnt vmcnt(6)" ::: "memory");   // tile0 resident
    __builtin_amdgcn_s_barrier();

    f32x4 acc[8][4] = {};
    for (int t = 0; t < NT; ++t) {
        const int cE = (t & 1) << 15;   // element offset of current buf
        const int cB = (t & 1) << 16;   // byte offset
        const int nB = cB ^ 65536;
        f16x8 a0[8], a1[8], bA[2], bB[2], bC[2], bD[2];
        // -------- phase 0: read a0 (A ks0) + bA (B ks0 nf01); stage B1(t+1)
#pragma unroll
        for (int mf = 0; mf < 8; ++mf)
            a0[mf] = *reinterpret_cast<const f16x8*>(&sm[cE + aBase + mf * 1024]);
#pragma unroll
        for (int q = 0; q < 2; ++q)
            bA[q] = *reinterpret_cast<const f16x8*>(&sm[cE + bBase + q * 1024]);
        if (t + 1 < NT) stB(nB, 1, t + 1);
        __builtin_amdgcn_s_barrier();
        asm volatile("s_waitcnt lgkmcnt(0)" ::: "memory");
        __builtin_amdgcn_sched_barrier(0);
        __builtin_amdgcn_s_setprio(1);
#pragma unroll
        for (int mf = 0; mf < 8; ++mf) {
            acc[mf][0] = __builtin_amdgcn_mfma_f32_16x16x32_f16(a0[mf], bA[0], acc[mf][0], 0, 0, 0);
            acc[mf][1] = __builtin_amdgcn_mfma_f32_16x16x32_f16(a0[mf], bA[1], acc[mf][1], 0, 0, 0);
        }
        __builtin_amdgcn_s_setprio(0);
        __builtin_amdgcn_s_barrier();
        // -------- phase 1: read a1 (A ks1) + bB (B ks0 nf23); MFMA a0xbB
#pragma unroll
        for (int mf = 0; mf < 8; ++mf)
            a1[mf] = *reinterpret_cast<const f16x8*>(&sm[cE + ((aBase + mf * 1024) ^ 32)]);
#pragma unroll
        for (int q = 0; q < 2; ++q)
            bB[q] = *reinterpret_cast<const f16x8*>(&sm[cE + bBase + (2 + q) * 1024]);
        __builtin_amdgcn_s_barrier();
        asm volatile("s_waitcnt lgkmcnt(0)" ::: "memory");  // drains a1 too
        __builtin_amdgcn_sched_barrier(0);
        __builtin_amdgcn_s_setprio(1);
#pragma unroll
        for (int mf = 0; mf < 8; ++mf) {
            acc[mf][2] = __builtin_amdgcn_mfma_f32_16x16x32_f16(a0[mf], bB[0], acc[mf][2], 0, 0, 0);
            acc[mf][3] = __builtin_amdgcn_mfma_f32_16x16x32_f16(a0[mf], bB[1], acc[mf][3], 0, 0, 0);
        }
        __builtin_amdgcn_s_setprio(0);
        __builtin_amdgcn_s_barrier();   // ALL waves have drained cur.A here
        // -------- phase 2: read bC,bD (B ks1); stage A0,A1(t+2) -> cur
#pragma unroll
        for (int q = 0; q < 2; ++q)
            bC[q] = *reinterpret_cast<const f16x8*>(&sm[cE + ((bBase + q * 1024) ^ 32)]);
#pragma unroll
        for (int q = 0; q < 2; ++q)
            bD[q] = *reinterpret_cast<const f16x8*>(&sm[cE + ((bBase + (2 + q) * 1024) ^ 32)]);
        if (t + 2 < NT) { stA(cB, 0, t + 2); stA(cB, 1, t + 2); }
        __builtin_amdgcn_s_barrier();
        asm volatile("s_waitcnt lgkmcnt(0)" ::: "memory");  // drains bC+bD
        __builtin_amdgcn_sched_barrier(0);
        __builtin_amdgcn_s_setprio(1);
#pragma unroll
        for (int mf = 0; mf < 8; ++mf) {
            acc[mf][0] = __builtin_amdgcn_mfma_f32_16x16x32_f16(a1[mf], bC[0], acc[mf][0], 0, 0, 0);
            acc[mf][1] = __builtin_amdgcn_mfma_f32_16x16x32_f16(a1[mf], bC[1], acc[mf][1], 0, 0, 0);
        }
        __builtin_amdgcn_s_setprio(0);
        __builtin_amdgcn_s_barrier();   // ALL waves have drained cur.B here
        // -------- phase 3: stage B0(t+2) -> cur; MFMA a1xbD (already drained)
        if (t + 2 < NT) stB(cB, 0, t + 2);
        __builtin_amdgcn_s_barrier();
        __builtin_amdgcn_s_setprio(1);
#pragma unroll
        for (int mf = 0; mf < 8; ++mf) {
            acc[mf][2] = __builtin_amdgcn_mfma_f32_16x16x32_f16(a1[mf], bD[0], acc[mf][2], 0, 0, 0);
            acc[mf][3] = __builtin_amdgcn_mfma_f32_16x16x32_f16(a1[mf], bD[1], acc[mf][3], 0, 0, 0);
        }
        __builtin_amdgcn_s_setprio(0);
        if (t < NT - 2) {
            asm volatile("s_waitcnt vmcnt(6)" ::: "memory"); // tile t+1 resident
        } else {
            asm volatile("s_waitcnt vmcnt(0)" ::: "memory"); // truncated stream tail
        }
        __builtin_amdgcn_s_barrier();
    }

    // ---------------------------------------------------------- epilogue
    const int rq = (lane >> 4) * 4;
    const int cl = lane & 15;
    if (MODE == 0) {
        const int seg = nx >> 2;                       // 0=Q 1=K 2=V (wave-uniform)
        const float* bias = seg == 0 ? bq : seg == 1 ? bk : bv;
        f16* outQK = seg == 0 ? Qo : Ko;
#pragma unroll
        for (int mf = 0; mf < 8; ++mf)
#pragma unroll
            for (int nf = 0; nf < 4; ++nf) {
                const long c = (nBase & 1023) + wni * 64 + nf * 16 + cl;
                const float bb = bias[c];
#pragma unroll
                for (int r = 0; r < 4; ++r) {
                    const long row = mBase + wmi * 128 + mf * 16 + rq + r;
                    const float v = acc[mf][nf][r] + bb;
                    if (seg < 2) {
                        outQK[row * 1024 + c] = (f16)v;
                    } else {
                        Vto[((row >> 11) * 1024 + c) * 2048 + (row & 2047)] = (f16)v;
                    }
                }
            }
    } else if (MODE == 1) {
        f16* o = o16 + oOff;
#pragma unroll
        for (int mf = 0; mf < 8; ++mf)
#pragma unroll
            for (int nf = 0; nf < 4; ++nf) {
                const long col = nBase + wni * 64 + nf * 16 + cl;
#pragma unroll
                for (int r = 0; r < 4; ++r) {
                    const long row = mBase + wmi * 128 + mf * 16 + rq + r;
                    o[row * 2048 + col] = (f16)acc[mf][nf][r];
                }
            }
    } else {
        float* o = o32 + oOff;
#pragma unroll
        for (int mf = 0; mf < 8; ++mf)
#pragma unroll
            for (int nf = 0; nf < 4; ++nf) {
                const long col = nBase + wni * 64 + nf * 16 + cl;
#pragma unroll
                for (int r = 0; r < 4; ++r) {
                    const long row = mBase + wmi * 128 + mf * 16 + rq + r;
                    o[row * 1024 + col] = acc[mf][nf][r];
                }
            }
    }
}

// ---------------------------------------------------------------- softmax
__global__ __launch_bounds__(256) void softmax_rows(const f16* __restrict__ S,
                                                    f16* __restrict__ P) {
    const long row = blockIdx.x;
    const int t = threadIdx.x;
    f16x8 a = reinterpret_cast<const f16x8*>(S + row * 2048)[t];
    float e[8];
    float m = -1e30f;
#pragma unroll
    for (int j = 0; j < 8; ++j) { e[j] = (float)a[j]; m = fmaxf(m, e[j]); }
#pragma unroll
    for (int o = 32; o > 0; o >>= 1) m = fmaxf(m, __shfl_down(m, o, 64));
    __shared__ float red[8];
    if ((t & 63) == 0) red[t >> 6] = m;
    __syncthreads();
    m = fmaxf(fmaxf(red[0], red[1]), fmaxf(red[2], red[3]));
    float s = 0.0f;
#pragma unroll
    for (int j = 0; j < 8; ++j) { e[j] = __expf(e[j] - m); s += e[j]; }
#pragma unroll
    for (int o = 32; o > 0; o >>= 1) s += __shfl_down(s, o, 64);
    if ((t & 63) == 0) red[4 + (t >> 6)] = s;
    __syncthreads();
    s = red[4] + red[5] + red[6] + red[7];
    float inv = 1.0f / s;
    f16x8 o;
#pragma unroll
    for (int j = 0; j < 8; ++j) o[j] = (f16)(e[j] * inv);
    reinterpret_cast<f16x8*>(P + row * 2048)[t] = o;
}

// ---------------------------------------------------------------- launch
extern "C" void kernel_launch(void* const* d_in, const int* in_sizes, int n_in,
                              void* d_out, int out_size, void* d_ws, size_t ws_size,
                              hipStream_t stream) {
    const float* x  = (const float*)d_in[0];
    const float* Wq = (const float*)d_in[1];
    const float* bq = (const float*)d_in[2];
    const float* Wk = (const float*)d_in[3];
    const float* bk = (const float*)d_in[4];
    const float* Wv = (const float*)d_in[5];
    const float* bv = (const float*)d_in[6];
    float* out = (float*)d_out;
    char* ws = (char*)d_ws;

    f16* Q   = (f16*)(ws + 0);                       // 32 MiB
    f16* Kb  = (f16*)(ws + 33554432);                // 32 MiB
    f16* Vt  = (f16*)(ws + 67108864);                // 32 MiB
    f16* S16 = (f16*)(ws + 100663296);               // 64 MiB (fp16 logits)
    f16* P   = (f16*)(ws + 167772160);               // 64 MiB (ends 224 MiB)
    f16* xh  = (f16*)(ws + 100663296);               // 32 MiB (dead before S16)
    f16* wt  = (f16*)(ws + 134217728);               //  6 MiB (dead before S16)

    cast_f32_f16<<<16384, 256, 0, stream>>>(x, xh);
    transpose_cast3<<<dim3(32, 32, 3), dim3(32, 8), 0, stream>>>(Wq, Wk, Wv, wt);

    // merged projections: M=16384, N=3072, K=1024 (768 blocks of 256x256)
    gemm256<0><<<768, 512, 0, stream>>>(xh, wt, nullptr, nullptr,
                                        bq, bk, bv, Q, Kb, Vt);

    // S16[b] = Q[b] @ K[b]^T : M=N=2048, K=1024 (512 blocks, fp16 out)
    gemm256<1><<<512, 512, 0, stream>>>(Q, Kb, S16, nullptr,
                                        nullptr, nullptr, nullptr,
                                        nullptr, nullptr, nullptr);

    softmax_rows<<<16384, 256, 0, stream>>>(S16, P);

    // out[b] = P[b] @ V[b] : M=2048, N=1024, K=2048 (256 blocks, fp32 out)
    gemm256<2><<<256, 512, 0, stream>>>(P, Vt, nullptr, out,
                                        nullptr, nullptr, nullptr,
                                        nullptr, nullptr, nullptr);
}

// Round 3
// 417.051 us; speedup vs baseline: 1.0152x; 1.0152x over previous
//
#include <hip/hip_runtime.h>
#include <hip/hip_bf16.h>
#include <stdint.h>

// SelfAttention: B=8, N=2048, D=DQ=DV=1024, fp32 in/out, fp16 MFMA internally.
// Round 9 -> 10: quadrant-pipelined phases. R8/R9 both hit 30% MfmaUtil because
// every phase was {reads -> barrier -> lgkmcnt(0) -> MFMA -> barrier}: strict
// LDS/MFMA alternation. Now phase p issues the ds_reads for quadrant p+1
// (ping-pong reg sets, disjoint per phase: B-frags read once per m-half) and
// immediately runs MFMA on quadrant p; compiler inserts fine-grained per-use
// lgkmcnt so reads stream UNDER the MFMA cluster. One barrier per phase.
//
// Per K-tile t (cur = buf[t&1], quadrants q=(m-half,k-half), 16 MFMA each):
//   P0: read q1 -> setY ; stage B1(t+1)->nxt ; MFMA q0 (setX) ; barrier
//   P1: read q2 -> setX ;                      MFMA q1 (setY) ; barrier
//   P2: read q3 -> setY ;                      MFMA q2 (setX) ; barrier
//   P3: vmcnt(0)  [8 outstanding loads, all >=3 phases old -> free drain;
//                  proves tile t+1 resident]
//       read q0(t+1) from nxt -> setX ; lgkmcnt(8)  [this wave's cur-reads
//                  drained -> cur regions free to restage]
//       stage A0,A1,B0(t+2)->cur ; MFMA q3 (setY) ; barrier
// Safety: nothing writes cur during P0-P2 (read reordering across those raw
// barriers is harmless); stages are pinned after vmcnt/lgkm asm (memory
// clobbers); global_load_lds has an LDS operand so LDS loads don't reorder
// across it. Cross-wave: stage data returns >=200cy after issue, issued after
// a barrier that follows every wave's read-issue (LDS queue FIFO) - same
// reliance as the verified m201 template.
//
// Workspace (224 MiB): unchanged layout.

typedef _Float16 f16;
typedef _Float16 f16x8 __attribute__((ext_vector_type(8)));
typedef _Float16 f16x4 __attribute__((ext_vector_type(4)));
typedef float f32x4 __attribute__((ext_vector_type(4)));

typedef __attribute__((address_space(3))) void lds_void;
typedef const __attribute__((address_space(1))) void gbl_void;

__device__ __forceinline__ void async16(void* l, const void* g) {
    __builtin_amdgcn_global_load_lds(
        reinterpret_cast<gbl_void*>(reinterpret_cast<uintptr_t>(g)),
        reinterpret_cast<lds_void*>(reinterpret_cast<uintptr_t>(l)),
        16, 0, 0);
}

// ---------------------------------------------------------------- cast x
__global__ __launch_bounds__(256) void cast_f32_f16(const float* __restrict__ x,
                                                    f16* __restrict__ y) {
    long i = (long)blockIdx.x * 256 + threadIdx.x;
    float4 v = reinterpret_cast<const float4*>(x)[i];
    f16x4 o = {(f16)v.x, (f16)v.y, (f16)v.z, (f16)v.w};
    reinterpret_cast<f16x4*>(y)[i] = o;
}

// ------------------------------------- transpose + cast Wq|Wk|Wv -> wt[3072][1024]
__global__ __launch_bounds__(256) void transpose_cast3(const float* __restrict__ W0,
                                                       const float* __restrict__ W1,
                                                       const float* __restrict__ W2,
                                                       f16* __restrict__ wt) {
    const float* W = blockIdx.z == 0 ? W0 : blockIdx.z == 1 ? W1 : W2;
    f16* o = wt + (long)blockIdx.z * 1024 * 1024;
    __shared__ float tile[32][33];
    int c0 = blockIdx.x * 32, r0 = blockIdx.y * 32;
    int tx = threadIdx.x, ty = threadIdx.y;
#pragma unroll
    for (int i = ty; i < 32; i += 8) tile[i][tx] = W[(long)(r0 + i) * 1024 + c0 + tx];
    __syncthreads();
#pragma unroll
    for (int i = ty; i < 32; i += 8) o[(long)(c0 + i) * 1024 + r0 + tx] = (f16)tile[tx][i];
}

// ---------------------------------------------------- 256x256 deep-pipe GEMM
// MODE 0: qkv  A=xh[16384x1024]   B=wt[3072x1024]   K=1024, grid 768
// MODE 1: qk^T A=Q  [b:2048x1024] B=Kb[b:2048x1024] K=1024, grid 512, f16 out
// MODE 2: pv   A=P  [b:2048x2048] B=Vt[b:1024x2048] K=2048, grid 256, f32 out
template <int MODE>
__global__ __launch_bounds__(512, 2) void gemm256(
    const f16* __restrict__ A, const f16* __restrict__ Bm,
    f16* __restrict__ o16, float* __restrict__ o32,
    const float* __restrict__ bq, const float* __restrict__ bk,
    const float* __restrict__ bv,
    f16* __restrict__ Qo, f16* __restrict__ Ko, f16* __restrict__ Vto) {
    constexpr int LDA = MODE == 2 ? 2048 : 1024;
    constexpr int LDB = MODE == 2 ? 2048 : 1024;
    constexpr int NT = (MODE == 2 ? 2048 : 1024) / 64;

    __shared__ f16 sm[65536];          // 128 KiB: [buf][A 32K | B 32K]
    char* smb = (char*)sm;

    const int tid = threadIdx.x;
    const int lane = tid & 63;
    const int wv = tid >> 6;           // 8 waves: 2M x 4N
    const int wmi = wv >> 2;           // 0..1  -> rows wmi*128
    const int wni = wv & 3;            // 0..3  -> cols wni*64

    const int L = blockIdx.x;
    long mBase, nBase, oOff = 0;
    int nx = 0;
    if (MODE == 0) {
        const int xcd = L & 7, j = L >> 3;   // j in [0,96): my fast, nx slow
        nx = j >> 3;
        mBase = (long)(xcd * 8 + (j & 7)) * 256;
        nBase = (long)nx * 256;
    } else if (MODE == 1) {
        const int b = L & 7, j = L >> 3;     // j in [0,64)
        mBase = (long)(j & 7) * 256;
        nBase = (long)(j >> 3) * 256;
        A += (long)b * 2048 * 1024;
        Bm += (long)b * 2048 * 1024;
        oOff = (long)b * 2048 * 2048;
    } else {
        const int b = L & 7, j = L >> 3;     // j in [0,32)
        mBase = (long)(j & 7) * 256;
        nBase = (long)(j >> 3) * 256;
        A += (long)b * 2048 * 2048;
        Bm += (long)b * 1024 * 2048;
        oOff = (long)b * 2048 * 1024;
    }

    // staging: unit = 128 rows x 64 cols f16 = 16KB; 2 async16/thread/unit.
    // LDS dest linear (wave-uniform + lane*16); source col pre-swizzled so
    // phys chunk c of row r holds global chunk c^(r&7).
    const int sru = tid >> 3;                    // 0..63
    const int sck = (tid & 7) ^ (sru & 7);       // swizzled source chunk
    const f16* pA = A + (mBase + sru) * LDA + sck * 8;
    const f16* pB = Bm + (nBase + sru) * LDB + sck * 8;

    auto stA = [&](int bufB, int half, int t) {
        const f16* s = pA + half * 128 * LDA + t * 64;
        char* d = smb + bufB + half * 16384 + tid * 16;
        async16(d, s);
        async16(d + 8192, s + 64 * LDA);
    };
    auto stB = [&](int bufB, int half, int t) {
        const f16* s = pB + half * 128 * LDB + t * 64;
        char* d = smb + bufB + 32768 + half * 16384 + tid * 16;
        async16(d, s);
        async16(d + 8192, s + 64 * LDB);
    };

    // fragment read bases (f16 element units); k-half toggle = ^32 (chunk ^4)
    const int pc0 = (lane >> 4) ^ (lane & 7);
    const int aBase = (wmi * 128 + (lane & 15)) * 64 + pc0 * 8;
    const int bBase = 16384 + (wni * 64 + (lane & 15)) * 64 + pc0 * 8;

    f32x4 acc[8][4] = {};
    f16x8 aX[4], bX[4], aY[4], bY[4];

    // quadrant readers: mh = m-half (a-frags mf = mh*4+i), ksx = 0 / 32
    auto rdA = [&](f16x8* dst, int cE, int mh, int ksx) {
#pragma unroll
        for (int i = 0; i < 4; ++i)
            dst[i] = *reinterpret_cast<const f16x8*>(
                &sm[cE + ((aBase + (mh * 4 + i) * 1024) ^ ksx)]);
    };
    auto rdB = [&](f16x8* dst, int cE, int ksx) {
#pragma unroll
        for (int q = 0; q < 4; ++q)
            dst[q] = *reinterpret_cast<const f16x8*>(
                &sm[cE + ((bBase + q * 1024) ^ ksx)]);
    };
    auto mm = [&](int mh, const f16x8* a, const f16x8* b) {
        __builtin_amdgcn_s_setprio(1);
#pragma unroll
        for (int i = 0; i < 4; ++i)
#pragma unroll
            for (int nf = 0; nf < 4; ++nf)
                acc[mh * 4 + i][nf] = __builtin_amdgcn_mfma_f32_16x16x32_f16(
                    a[i], b[nf], acc[mh * 4 + i][nf], 0, 0, 0);
        __builtin_amdgcn_s_setprio(0);
    };

    // prologue: tile0 {A0,A1,B0,B1} -> buf0, tile1 {A0,A1,B0} -> buf1
    stA(0, 0, 0); stA(0, 1, 0); stB(0, 0, 0); stB(0, 1, 0);
    stA(65536, 0, 1); stA(65536, 1, 1); stB(65536, 0, 1);
    asm volatile("s_waitcnt vmcnt(6)" ::: "memory");   // tile0 resident
    __builtin_amdgcn_s_barrier();
    rdA(aX, 0, 0, 0); rdB(bX, 0, 0);                   // q0 of tile 0

    for (int t = 0; t < NT; ++t) {
        const int cE = (t & 1) << 15;   // element offset of current buf
        const int cB = (t & 1) << 16;   // byte offset
        const int nB = cB ^ 65536;
        // -------- P0: read q1; stage B1(t+1)->nxt; MFMA q0
        rdA(aY, cE, 1, 0); rdB(bY, cE, 0);
        if (t + 1 < NT) stB(nB, 1, t + 1);
        mm(0, aX, bX);
        __builtin_amdgcn_s_barrier();
        // -------- P1: read q2; MFMA q1
        rdA(aX, cE, 0, 32); rdB(bX, cE, 32);
        mm(1, aY, bY);
        __builtin_amdgcn_s_barrier();
        // -------- P2: read q3; MFMA q2
        rdA(aY, cE, 1, 32); rdB(bY, cE, 32);
        mm(0, aX, bX);
        __builtin_amdgcn_s_barrier();
        // -------- P3: tile boundary + pre-read q0(t+1); stage t+2; MFMA q3
        asm volatile("s_waitcnt vmcnt(0)" ::: "memory"); // all >=3 phases old
        if (t + 1 < NT) {
            rdA(aX, cE ^ 32768, 0, 0); rdB(bX, cE ^ 32768, 0);
            asm volatile("s_waitcnt lgkmcnt(8)" ::: "memory"); // cur drained
        } else {
            asm volatile("s_waitcnt lgkmcnt(0)" ::: "memory");
        }
        if (t + 2 < NT) { stA(cB, 0, t + 2); stA(cB, 1, t + 2); stB(cB, 0, t + 2); }
        mm(1, aY, bY);
        __builtin_amdgcn_s_barrier();
    }

    // ---------------------------------------------------------- epilogue
    const int rq = (lane >> 4) * 4;
    const int cl = lane & 15;
    if (MODE == 0) {
        const int seg = nx >> 2;                       // 0=Q 1=K 2=V (wave-uniform)
        const float* bias = seg == 0 ? bq : seg == 1 ? bk : bv;
        f16* outQK = seg == 0 ? Qo : Ko;
#pragma unroll
        for (int mf = 0; mf < 8; ++mf)
#pragma unroll
            for (int nf = 0; nf < 4; ++nf) {
                const long c = (nBase & 1023) + wni * 64 + nf * 16 + cl;
                const float bb = bias[c];
#pragma unroll
                for (int r = 0; r < 4; ++r) {
                    const long row = mBase + wmi * 128 + mf * 16 + rq + r;
                    const float v = acc[mf][nf][r] + bb;
                    if (seg < 2) {
                        outQK[row * 1024 + c] = (f16)v;
                    } else {
                        Vto[((row >> 11) * 1024 + c) * 2048 + (row & 2047)] = (f16)v;
                    }
                }
            }
    } else if (MODE == 1) {
        f16* o = o16 + oOff;
#pragma unroll
        for (int mf = 0; mf < 8; ++mf)
#pragma unroll
            for (int nf = 0; nf < 4; ++nf) {
                const long col = nBase + wni * 64 + nf * 16 + cl;
#pragma unroll
                for (int r = 0; r < 4; ++r) {
                    const long row = mBase + wmi * 128 + mf * 16 + rq + r;
                    o[row * 2048 + col] = (f16)acc[mf][nf][r];
                }
            }
    } else {
        float* o = o32 + oOff;
#pragma unroll
        for (int mf = 0; mf < 8; ++mf)
#pragma unroll
            for (int nf = 0; nf < 4; ++nf) {
                const long col = nBase + wni * 64 + nf * 16 + cl;
#pragma unroll
                for (int r = 0; r < 4; ++r) {
                    const long row = mBase + wmi * 128 + mf * 16 + rq + r;
                    o[row * 1024 + col] = acc[mf][nf][r];
                }
            }
    }
}

// ---------------------------------------------------------------- softmax
__global__ __launch_bounds__(256) void softmax_rows(const f16* __restrict__ S,
                                                    f16* __restrict__ P) {
    const long row = blockIdx.x;
    const int t = threadIdx.x;
    f16x8 a = reinterpret_cast<const f16x8*>(S + row * 2048)[t];
    float e[8];
    float m = -1e30f;
#pragma unroll
    for (int j = 0; j < 8; ++j) { e[j] = (float)a[j]; m = fmaxf(m, e[j]); }
#pragma unroll
    for (int o = 32; o > 0; o >>= 1) m = fmaxf(m, __shfl_down(m, o, 64));
    __shared__ float red[8];
    if ((t & 63) == 0) red[t >> 6] = m;
    __syncthreads();
    m = fmaxf(fmaxf(red[0], red[1]), fmaxf(red[2], red[3]));
    float s = 0.0f;
#pragma unroll
    for (int j = 0; j < 8; ++j) { e[j] = __expf(e[j] - m); s += e[j]; }
#pragma unroll
    for (int o = 32; o > 0; o >>= 1) s += __shfl_down(s, o, 64);
    if ((t & 63) == 0) red[4 + (t >> 6)] = s;
    __syncthreads();
    s = red[4] + red[5] + red[6] + red[7];
    float inv = 1.0f / s;
    f16x8 o;
#pragma unroll
    for (int j = 0; j < 8; ++j) o[j] = (f16)(e[j] * inv);
    reinterpret_cast<f16x8*>(P + row * 2048)[t] = o;
}

// ---------------------------------------------------------------- launch
extern "C" void kernel_launch(void* const* d_in, const int* in_sizes, int n_in,
                              void* d_out, int out_size, void* d_ws, size_t ws_size,
                              hipStream_t stream) {
    const float* x  = (const float*)d_in[0];
    const float* Wq = (const float*)d_in[1];
    const float* bq = (const float*)d_in[2];
    const float* Wk = (const float*)d_in[3];
    const float* bk = (const float*)d_in[4];
    const float* Wv = (const float*)d_in[5];
    const float* bv = (const float*)d_in[6];
    float* out = (float*)d_out;
    char* ws = (char*)d_ws;

    f16* Q   = (f16*)(ws + 0);                       // 32 MiB
    f16* Kb  = (f16*)(ws + 33554432);                // 32 MiB
    f16* Vt  = (f16*)(ws + 67108864);                // 32 MiB
    f16* S16 = (f16*)(ws + 100663296);               // 64 MiB (fp16 logits)
    f16* P   = (f16*)(ws + 167772160);               // 64 MiB (ends 224 MiB)
    f16* xh  = (f16*)(ws + 100663296);               // 32 MiB (dead before S16)
    f16* wt  = (f16*)(ws + 134217728);               //  6 MiB (dead before S16)

    cast_f32_f16<<<16384, 256, 0, stream>>>(x, xh);
    transpose_cast3<<<dim3(32, 32, 3), dim3(32, 8), 0, stream>>>(Wq, Wk, Wv, wt);

    // merged projections: M=16384, N=3072, K=1024 (768 blocks of 256x256)
    gemm256<0><<<768, 512, 0, stream>>>(xh, wt, nullptr, nullptr,
                                        bq, bk, bv, Q, Kb, Vt);

    // S16[b] = Q[b] @ K[b]^T : M=N=2048, K=1024 (512 blocks, fp16 out)
    gemm256<1><<<512, 512, 0, stream>>>(Q, Kb, S16, nullptr,
                                        nullptr, nullptr, nullptr,
                                        nullptr, nullptr, nullptr);

    softmax_rows<<<16384, 256, 0, stream>>>(S16, P);

    // out[b] = P[b] @ V[b] : M=2048, N=1024, K=2048 (256 blocks, fp32 out)
    gemm256<2><<<256, 512, 0, stream>>>(P, Vt, nullptr, out,
                                        nullptr, nullptr, nullptr,
                                        nullptr, nullptr, nullptr);
}

// Round 5
// 399.107 us; speedup vs baseline: 1.0608x; 1.0450x over previous
//
#include <hip/hip_runtime.h>
#include <hip/hip_bf16.h>
#include <stdint.h>

// SelfAttention: B=8, N=2048, D=DQ=DV=1024, fp32 in/out, fp16 MFMA internally.
// Round 11 -> 12: REVERT to the R8 kernel (best passing, 402us) and remove the
// two scheduling hints it carried:
//  (1) sched_barrier(0) after each pre-MFMA lgkmcnt(0): pinned the whole MFMA
//      cluster below a FULL read drain. Without it the compiler's fine-grained
//      per-operand lgkmcnt lets early MFMAs start while later reads stream in
//      (the m201 template has no sched_barrier here).
//  (2) s_setprio around MFMA clusters: with 2 waves/SIMD in lockstep this can
//      starve the sibling wave's read-issue (m190 measured setprio negative on
//      barrier-locked GEMM).
// Everything else (staging ledger, vmcnt placement, race-freedom drains,
// fragment maps, epilogues) is byte-identical to the passing R8 kernel.
//
// Pipeline safety (per K-tile t, cur = buf[t&1], nxt = cur^1):
//   ph0: ds_read a0(A ks0), bA(B ks0 nf01), a1(A ks1)  [all of cur.A read here]
//        stage (t+1,B1) -> nxt  (disjoint buffer)
//        MFMA(ks0,nf01); lgkmcnt(0) drains a1 before barrier.
//   ph1: ds_read bB(ks0 nf23); stage (t+2,A0) -> cur.A0
//        [safe: all A reads drained ph0-end, barrier separates]
//   ph2: ds_read bC,bD(ks1);   stage (t+2,A1) -> cur.A1 ; drain bD at end.
//   ph3: stage (t+2,B0) -> cur.B0  [all B reads drained by ph2-end]
//        end-of-tile: vmcnt(6) = 3 units in flight -> tile t+1 fully resident
//        (vmcnt(0) for the last two tiles where the stream is truncated).
// Prologue stages 7 units (tile0 full + tile1 A0,A1,B0), vmcnt(6).
//
// Workspace (224 MiB): unchanged layout.

typedef _Float16 f16;
typedef _Float16 f16x8 __attribute__((ext_vector_type(8)));
typedef _Float16 f16x4 __attribute__((ext_vector_type(4)));
typedef float f32x4 __attribute__((ext_vector_type(4)));

typedef __attribute__((address_space(3))) void lds_void;
typedef const __attribute__((address_space(1))) void gbl_void;

__device__ __forceinline__ void async16(void* l, const void* g) {
    __builtin_amdgcn_global_load_lds(
        reinterpret_cast<gbl_void*>(reinterpret_cast<uintptr_t>(g)),
        reinterpret_cast<lds_void*>(reinterpret_cast<uintptr_t>(l)),
        16, 0, 0);
}

// ---------------------------------------------------------------- cast x
__global__ __launch_bounds__(256) void cast_f32_f16(const float* __restrict__ x,
                                                    f16* __restrict__ y) {
    long i = (long)blockIdx.x * 256 + threadIdx.x;
    float4 v = reinterpret_cast<const float4*>(x)[i];
    f16x4 o = {(f16)v.x, (f16)v.y, (f16)v.z, (f16)v.w};
    reinterpret_cast<f16x4*>(y)[i] = o;
}

// ------------------------------------- transpose + cast Wq|Wk|Wv -> wt[3072][1024]
__global__ __launch_bounds__(256) void transpose_cast3(const float* __restrict__ W0,
                                                       const float* __restrict__ W1,
                                                       const float* __restrict__ W2,
                                                       f16* __restrict__ wt) {
    const float* W = blockIdx.z == 0 ? W0 : blockIdx.z == 1 ? W1 : W2;
    f16* o = wt + (long)blockIdx.z * 1024 * 1024;
    __shared__ float tile[32][33];
    int c0 = blockIdx.x * 32, r0 = blockIdx.y * 32;
    int tx = threadIdx.x, ty = threadIdx.y;
#pragma unroll
    for (int i = ty; i < 32; i += 8) tile[i][tx] = W[(long)(r0 + i) * 1024 + c0 + tx];
    __syncthreads();
#pragma unroll
    for (int i = ty; i < 32; i += 8) o[(long)(c0 + i) * 1024 + r0 + tx] = (f16)tile[tx][i];
}

// ---------------------------------------------------- 256x256 deep-pipe GEMM
// MODE 0: qkv  A=xh[16384x1024]   B=wt[3072x1024]   K=1024, grid 768
// MODE 1: qk^T A=Q  [b:2048x1024] B=Kb[b:2048x1024] K=1024, grid 512, f16 out
// MODE 2: pv   A=P  [b:2048x2048] B=Vt[b:1024x2048] K=2048, grid 256, f32 out
template <int MODE>
__global__ __launch_bounds__(512, 2) void gemm256(
    const f16* __restrict__ A, const f16* __restrict__ Bm,
    f16* __restrict__ o16, float* __restrict__ o32,
    const float* __restrict__ bq, const float* __restrict__ bk,
    const float* __restrict__ bv,
    f16* __restrict__ Qo, f16* __restrict__ Ko, f16* __restrict__ Vto) {
    constexpr int LDA = MODE == 2 ? 2048 : 1024;
    constexpr int LDB = MODE == 2 ? 2048 : 1024;
    constexpr int NT = (MODE == 2 ? 2048 : 1024) / 64;

    __shared__ f16 sm[65536];          // 128 KiB: [buf][A 32K | B 32K]
    char* smb = (char*)sm;

    const int tid = threadIdx.x;
    const int lane = tid & 63;
    const int wv = tid >> 6;           // 8 waves: 2M x 4N
    const int wmi = wv >> 2;           // 0..1  -> rows wmi*128
    const int wni = wv & 3;            // 0..3  -> cols wni*64

    const int L = blockIdx.x;
    long mBase, nBase, oOff = 0;
    int nx = 0;
    if (MODE == 0) {
        const int xcd = L & 7, j = L >> 3;   // j in [0,96): my fast, nx slow
        nx = j >> 3;
        mBase = (long)(xcd * 8 + (j & 7)) * 256;
        nBase = (long)nx * 256;
    } else if (MODE == 1) {
        const int b = L & 7, j = L >> 3;     // j in [0,64)
        mBase = (long)(j & 7) * 256;
        nBase = (long)(j >> 3) * 256;
        A += (long)b * 2048 * 1024;
        Bm += (long)b * 2048 * 1024;
        oOff = (long)b * 2048 * 2048;
    } else {
        const int b = L & 7, j = L >> 3;     // j in [0,32)
        mBase = (long)(j & 7) * 256;
        nBase = (long)(j >> 3) * 256;
        A += (long)b * 2048 * 2048;
        Bm += (long)b * 1024 * 2048;
        oOff = (long)b * 2048 * 1024;
    }

    // staging: unit = 128 rows x 64 cols f16 = 16KB; 2 async16/thread/unit.
    // LDS dest linear (wave-uniform + lane*16); source col pre-swizzled so
    // phys chunk c of row r holds global chunk c^(r&7).
    const int sru = tid >> 3;                    // 0..63
    const int sck = (tid & 7) ^ (sru & 7);       // swizzled source chunk
    const f16* pA = A + (mBase + sru) * LDA + sck * 8;
    const f16* pB = Bm + (nBase + sru) * LDB + sck * 8;

    auto stA = [&](int bufB, int half, int t) {
        const f16* s = pA + half * 128 * LDA + t * 64;
        char* d = smb + bufB + half * 16384 + tid * 16;
        async16(d, s);
        async16(d + 8192, s + 64 * LDA);
    };
    auto stB = [&](int bufB, int half, int t) {
        const f16* s = pB + half * 128 * LDB + t * 64;
        char* d = smb + bufB + 32768 + half * 16384 + tid * 16;
        async16(d, s);
        async16(d + 8192, s + 64 * LDB);
    };

    // fragment read bases (f16 element units); ks toggle = ^32 (chunk ^4)
    const int pc0 = (lane >> 4) ^ (lane & 7);
    const int aBase = (wmi * 128 + (lane & 15)) * 64 + pc0 * 8;
    const int bBase = 16384 + (wni * 64 + (lane & 15)) * 64 + pc0 * 8;

    // prologue: tile0 {A0,A1,B0,B1} -> buf0, tile1 {A0,A1,B0} -> buf1
    stA(0, 0, 0); stA(0, 1, 0); stB(0, 0, 0); stB(0, 1, 0);
    stA(65536, 0, 1); stA(65536, 1, 1); stB(65536, 0, 1);
    asm volatile("s_waitcnt vmcnt(6)" ::: "memory");   // tile0 resident
    __builtin_amdgcn_s_barrier();

    f32x4 acc[8][4] = {};
    for (int t = 0; t < NT; ++t) {
        const int cE = (t & 1) << 15;   // element offset of current buf
        const int cB = (t & 1) << 16;   // byte offset
        const int nB = cB ^ 65536;
        f16x8 a0[8], a1[8], bA[2], bB[2], bC[2], bD[2];
        // -------- phase 0: all A reads + B(ks0,nf01); stage (t+1,B1)->nxt
#pragma unroll
        for (int mf = 0; mf < 8; ++mf)
            a0[mf] = *reinterpret_cast<const f16x8*>(&sm[cE + aBase + mf * 1024]);
#pragma unroll
        for (int q = 0; q < 2; ++q)
            bA[q] = *reinterpret_cast<const f16x8*>(&sm[cE + bBase + q * 1024]);
#pragma unroll
        for (int mf = 0; mf < 8; ++mf)
            a1[mf] = *reinterpret_cast<const f16x8*>(&sm[cE + ((aBase + mf * 1024) ^ 32)]);
        if (t + 1 < NT) stB(nB, 1, t + 1);
        __builtin_amdgcn_s_barrier();
        asm volatile("s_waitcnt lgkmcnt(8)" ::: "memory");  // a0,bA ready; a1 in flight
#pragma unroll
        for (int mf = 0; mf < 8; ++mf) {
            acc[mf][0] = __builtin_amdgcn_mfma_f32_16x16x32_f16(a0[mf], bA[0], acc[mf][0], 0, 0, 0);
            acc[mf][1] = __builtin_amdgcn_mfma_f32_16x16x32_f16(a0[mf], bA[1], acc[mf][1], 0, 0, 0);
        }
        asm volatile("s_waitcnt lgkmcnt(0)" ::: "memory");  // drain a1: A region free
        __builtin_amdgcn_s_barrier();
        // -------- phase 1: B(ks0,nf23); stage (t+2,A0)->cur
#pragma unroll
        for (int q = 0; q < 2; ++q)
            bB[q] = *reinterpret_cast<const f16x8*>(&sm[cE + bBase + (2 + q) * 1024]);
        if (t + 2 < NT) stA(cB, 0, t + 2);
        __builtin_amdgcn_s_barrier();
        asm volatile("s_waitcnt lgkmcnt(0)" ::: "memory");
#pragma unroll
        for (int mf = 0; mf < 8; ++mf) {
            acc[mf][2] = __builtin_amdgcn_mfma_f32_16x16x32_f16(a0[mf], bB[0], acc[mf][2], 0, 0, 0);
            acc[mf][3] = __builtin_amdgcn_mfma_f32_16x16x32_f16(a0[mf], bB[1], acc[mf][3], 0, 0, 0);
        }
        __builtin_amdgcn_s_barrier();
        // -------- phase 2: B(ks1,nf0..3); stage (t+2,A1)->cur
#pragma unroll
        for (int q = 0; q < 2; ++q)
            bC[q] = *reinterpret_cast<const f16x8*>(&sm[cE + ((bBase + q * 1024) ^ 32)]);
#pragma unroll
        for (int q = 0; q < 2; ++q)
            bD[q] = *reinterpret_cast<const f16x8*>(&sm[cE + ((bBase + (2 + q) * 1024) ^ 32)]);
        if (t + 2 < NT) stA(cB, 1, t + 2);
        __builtin_amdgcn_s_barrier();
        asm volatile("s_waitcnt lgkmcnt(2)" ::: "memory");  // bC ready; bD in flight
#pragma unroll
        for (int mf = 0; mf < 8; ++mf) {
            acc[mf][0] = __builtin_amdgcn_mfma_f32_16x16x32_f16(a1[mf], bC[0], acc[mf][0], 0, 0, 0);
            acc[mf][1] = __builtin_amdgcn_mfma_f32_16x16x32_f16(a1[mf], bC[1], acc[mf][1], 0, 0, 0);
        }
        asm volatile("s_waitcnt lgkmcnt(0)" ::: "memory");  // drain bD: B region free
        __builtin_amdgcn_s_barrier();
        // -------- phase 3: stage (t+2,B0)->cur; end-of-tile counted vmcnt
        if (t + 2 < NT) stB(cB, 0, t + 2);
        __builtin_amdgcn_s_barrier();
#pragma unroll
        for (int mf = 0; mf < 8; ++mf) {
            acc[mf][2] = __builtin_amdgcn_mfma_f32_16x16x32_f16(a1[mf], bD[0], acc[mf][2], 0, 0, 0);
            acc[mf][3] = __builtin_amdgcn_mfma_f32_16x16x32_f16(a1[mf], bD[1], acc[mf][3], 0, 0, 0);
        }
        if (t < NT - 2) {
            asm volatile("s_waitcnt vmcnt(6)" ::: "memory"); // tile t+1 resident
        } else {
            asm volatile("s_waitcnt vmcnt(0)" ::: "memory"); // truncated stream tail
        }
        __builtin_amdgcn_s_barrier();
    }

    // ---------------------------------------------------------- epilogue
    const int rq = (lane >> 4) * 4;
    const int cl = lane & 15;
    if (MODE == 0) {
        const int seg = nx >> 2;                       // 0=Q 1=K 2=V (wave-uniform)
        const float* bias = seg == 0 ? bq : seg == 1 ? bk : bv;
        f16* outQK = seg == 0 ? Qo : Ko;
#pragma unroll
        for (int mf = 0; mf < 8; ++mf)
#pragma unroll
            for (int nf = 0; nf < 4; ++nf) {
                const long c = (nBase & 1023) + wni * 64 + nf * 16 + cl;
                const float bb = bias[c];
#pragma unroll
                for (int r = 0; r < 4; ++r) {
                    const long row = mBase + wmi * 128 + mf * 16 + rq + r;
                    const float v = acc[mf][nf][r] + bb;
                    if (seg < 2) {
                        outQK[row * 1024 + c] = (f16)v;
                    } else {
                        Vto[((row >> 11) * 1024 + c) * 2048 + (row & 2047)] = (f16)v;
                    }
                }
            }
    } else if (MODE == 1) {
        f16* o = o16 + oOff;
#pragma unroll
        for (int mf = 0; mf < 8; ++mf)
#pragma unroll
            for (int nf = 0; nf < 4; ++nf) {
                const long col = nBase + wni * 64 + nf * 16 + cl;
#pragma unroll
                for (int r = 0; r < 4; ++r) {
                    const long row = mBase + wmi * 128 + mf * 16 + rq + r;
                    o[row * 2048 + col] = (f16)acc[mf][nf][r];
                }
            }
    } else {
        float* o = o32 + oOff;
#pragma unroll
        for (int mf = 0; mf < 8; ++mf)
#pragma unroll
            for (int nf = 0; nf < 4; ++nf) {
                const long col = nBase + wni * 64 + nf * 16 + cl;
#pragma unroll
                for (int r = 0; r < 4; ++r) {
                    const long row = mBase + wmi * 128 + mf * 16 + rq + r;
                    o[row * 1024 + col] = acc[mf][nf][r];
                }
            }
    }
}

// ---------------------------------------------------------------- softmax
__global__ __launch_bounds__(256) void softmax_rows(const f16* __restrict__ S,
                                                    f16* __restrict__ P) {
    const long row = blockIdx.x;
    const int t = threadIdx.x;
    f16x8 a = reinterpret_cast<const f16x8*>(S + row * 2048)[t];
    float e[8];
    float m = -1e30f;
#pragma unroll
    for (int j = 0; j < 8; ++j) { e[j] = (float)a[j]; m = fmaxf(m, e[j]); }
#pragma unroll
    for (int o = 32; o > 0; o >>= 1) m = fmaxf(m, __shfl_down(m, o, 64));
    __shared__ float red[8];
    if ((t & 63) == 0) red[t >> 6] = m;
    __syncthreads();
    m = fmaxf(fmaxf(red[0], red[1]), fmaxf(red[2], red[3]));
    float s = 0.0f;
#pragma unroll
    for (int j = 0; j < 8; ++j) { e[j] = __expf(e[j] - m); s += e[j]; }
#pragma unroll
    for (int o = 32; o > 0; o >>= 1) s += __shfl_down(s, o, 64);
    if ((t & 63) == 0) red[4 + (t >> 6)] = s;
    __syncthreads();
    s = red[4] + red[5] + red[6] + red[7];
    float inv = 1.0f / s;
    f16x8 o;
#pragma unroll
    for (int j = 0; j < 8; ++j) o[j] = (f16)(e[j] * inv);
    reinterpret_cast<f16x8*>(P + row * 2048)[t] = o;
}

// ---------------------------------------------------------------- launch
extern "C" void kernel_launch(void* const* d_in, const int* in_sizes, int n_in,
                              void* d_out, int out_size, void* d_ws, size_t ws_size,
                              hipStream_t stream) {
    const float* x  = (const float*)d_in[0];
    const float* Wq = (const float*)d_in[1];
    const float* bq = (const float*)d_in[2];
    const float* Wk = (const float*)d_in[3];
    const float* bk = (const float*)d_in[4];
    const float* Wv = (const float*)d_in[5];
    const float* bv = (const float*)d_in[6];
    float* out = (float*)d_out;
    char* ws = (char*)d_ws;

    f16* Q   = (f16*)(ws + 0);                       // 32 MiB
    f16* Kb  = (f16*)(ws + 33554432);                // 32 MiB
    f16* Vt  = (f16*)(ws + 67108864);                // 32 MiB
    f16* S16 = (f16*)(ws + 100663296);               // 64 MiB (fp16 logits)
    f16* P   = (f16*)(ws + 167772160);               // 64 MiB (ends 224 MiB)
    f16* xh  = (f16*)(ws + 100663296);               // 32 MiB (dead before S16)
    f16* wt  = (f16*)(ws + 134217728);               //  6 MiB (dead before S16)

    cast_f32_f16<<<16384, 256, 0, stream>>>(x, xh);
    transpose_cast3<<<dim3(32, 32, 3), dim3(32, 8), 0, stream>>>(Wq, Wk, Wv, wt);

    // merged projections: M=16384, N=3072, K=1024 (768 blocks of 256x256)
    gemm256<0><<<768, 512, 0, stream>>>(xh, wt, nullptr, nullptr,
                                        bq, bk, bv, Q, Kb, Vt);

    // S16[b] = Q[b] @ K[b]^T : M=N=2048, K=1024 (512 blocks, fp16 out)
    gemm256<1><<<512, 512, 0, stream>>>(Q, Kb, S16, nullptr,
                                        nullptr, nullptr, nullptr,
                                        nullptr, nullptr, nullptr);

    softmax_rows<<<16384, 256, 0, stream>>>(S16, P);

    // out[b] = P[b] @ V[b] : M=2048, N=1024, K=2048 (256 blocks, fp32 out)
    gemm256<2><<<256, 512, 0, stream>>>(P, Vt, nullptr, out,
                                        nullptr, nullptr, nullptr,
                                        nullptr, nullptr, nullptr);
}